// Round 1
// baseline (40.975 us; speedup 1.0000x reference)
//
#include <hip/hip_runtime.h>

// Reduced model: both attention blocks have zero K-projection -> uniform
// softmax -> attn@v == column-mean of v. Every row of each layer's output
// depends only on its token id and the global token histogram. Output is
// row 0 of layer-2 output dotted with ow.
//
// Input order (setup_inputs dict order):
//  0: w        int32 [S]
//  1: emb      f32 [3,8]
//  2: l1_in_w  f32 [48,16]   3: l1_in_b f32 [48]
//  4: l1_out_w f32 [16,16]   5: l1_out_b f32 [16]
//  6: l1_w1    f32 [16,16]   7: l1_b1   f32 [16]
//  8: l1_w2    f32 [16,16]   9: l1_b2   f32 [16]
// 10: l2_in_w  f32 [48,16]  11: l2_in_b f32 [48]
// 12: l2_out_w f32 [16,16]  13: l2_out_b f32 [16]
// 14: l2_w1    f32 [16,16]  15: l2_b1   f32 [16]
// 16: l2_w2    f32 [16,16]  17: l2_b2   f32 [16]
// 18: ow       f32 [1,16]   19: ob     f32 [1]

__device__ __forceinline__ void ln16(const float* x, float* out) {
    float mean = 0.f, msq = 0.f;
    #pragma unroll
    for (int j = 0; j < 16; ++j) { mean += x[j]; msq += x[j] * x[j]; }
    mean *= (1.f / 16.f);
    msq  *= (1.f / 16.f);
    float inv = 1.f / sqrtf(msq - mean * mean);
    #pragma unroll
    for (int j = 0; j < 16; ++j) out[j] = (x[j] - mean) * inv;
}

// One transformer layer for a single row, given the mean of the layer's
// input over all rows (uniform attention => attn@v = mean_v).
__device__ __forceinline__ void layer_row(
    const float* __restrict__ src, const float* __restrict__ meansrc,
    const float* __restrict__ in_w, const float* __restrict__ in_b,
    const float* __restrict__ out_w, const float* __restrict__ out_b,
    const float* __restrict__ w1, const float* __restrict__ b1,
    const float* __restrict__ w2, const float* __restrict__ b2,
    float* __restrict__ out)
{
    float vmean[16], a[16], x[16], h[16], r[16], y[16];
    // v projection of the mean row: vw = in_w rows 32..47, vb = in_b[32..]
    #pragma unroll
    for (int j = 0; j < 16; ++j) {
        float acc = in_b[32 + j];
        for (int k = 0; k < 16; ++k) acc += meansrc[k] * in_w[(32 + j) * 16 + k];
        vmean[j] = acc;
    }
    // out projection
    #pragma unroll
    for (int j = 0; j < 16; ++j) {
        float acc = out_b[j];
        for (int k = 0; k < 16; ++k) acc += vmean[k] * out_w[j * 16 + k];
        a[j] = acc;
    }
    #pragma unroll
    for (int j = 0; j < 16; ++j) x[j] = src[j] + a[j];
    ln16(x, h);
    // feed-forward
    #pragma unroll
    for (int j = 0; j < 16; ++j) {
        float acc = b1[j];
        for (int k = 0; k < 16; ++k) acc += h[k] * w1[j * 16 + k];
        r[j] = acc > 0.f ? acc : 0.f;
    }
    #pragma unroll
    for (int j = 0; j < 16; ++j) {
        float acc = b2[j];
        for (int k = 0; k < 16; ++k) acc += r[k] * w2[j * 16 + k];
        y[j] = h[j] + acc;
    }
    ln16(y, out);
}

__global__ void __launch_bounds__(256)
model_kernel(const int* __restrict__ w, int S,
             const float* __restrict__ emb,
             const float* __restrict__ l1_in_w, const float* __restrict__ l1_in_b,
             const float* __restrict__ l1_out_w, const float* __restrict__ l1_out_b,
             const float* __restrict__ l1_w1, const float* __restrict__ l1_b1,
             const float* __restrict__ l1_w2, const float* __restrict__ l1_b2,
             const float* __restrict__ l2_in_w, const float* __restrict__ l2_in_b,
             const float* __restrict__ l2_out_w, const float* __restrict__ l2_out_b,
             const float* __restrict__ l2_w1, const float* __restrict__ l2_b1,
             const float* __restrict__ l2_w2, const float* __restrict__ l2_b2,
             const float* __restrict__ ow, const float* __restrict__ ob,
             float* __restrict__ out)
{
    __shared__ int cnt[3];
    __shared__ float rows[3][16];
    const int tid = threadIdx.x;
    if (tid < 3) cnt[tid] = 0;
    __syncthreads();

    // histogram of tokens (values are 0..2 by construction)
    int c0 = 0, c1 = 0, c2 = 0;
    for (int i = tid; i < S; i += blockDim.x) {
        int t = w[i];
        c0 += (t == 0); c1 += (t == 1); c2 += (t == 2);
    }
    if (c0) atomicAdd(&cnt[0], c0);
    if (c1) atomicAdd(&cnt[1], c1);
    if (c2) atomicAdd(&cnt[2], c2);
    __syncthreads();

    if (tid != 0) return;

    const float invS = 1.f / (float)S;
    float p[3] = { cnt[0] * invS, cnt[1] * invS, cnt[2] * invS };

    // mean input row of layer 1: sum_t p_t * [emb[t], -emb[t]]
    float meansrc[16];
    #pragma unroll
    for (int j = 0; j < 8; ++j) {
        float m = p[0] * emb[0 * 8 + j] + p[1] * emb[1 * 8 + j] + p[2] * emb[2 * 8 + j];
        meansrc[j] = m; meansrc[8 + j] = -m;
    }

    // layer-1 output for each of the 3 token types
    for (int t = 0; t < 3; ++t) {
        float src0[16];
        #pragma unroll
        for (int j = 0; j < 8; ++j) { src0[j] = emb[t * 8 + j]; src0[8 + j] = -emb[t * 8 + j]; }
        layer_row(src0, meansrc,
                  l1_in_w, l1_in_b, l1_out_w, l1_out_b,
                  l1_w1, l1_b1, l1_w2, l1_b2, rows[t]);
    }

    // mean input row of layer 2
    float meansrc1[16];
    #pragma unroll
    for (int j = 0; j < 16; ++j)
        meansrc1[j] = p[0] * rows[0][j] + p[1] * rows[1][j] + p[2] * rows[2][j];

    const int t0 = w[0];
    float fin[16];
    layer_row(rows[t0], meansrc1,
              l2_in_w, l2_in_b, l2_out_w, l2_out_b,
              l2_w1, l2_b1, l2_w2, l2_b2, fin);

    float acc = ob[0];
    #pragma unroll
    for (int k = 0; k < 16; ++k) acc += fin[k] * ow[k];
    out[0] = acc;
}

extern "C" void kernel_launch(void* const* d_in, const int* in_sizes, int n_in,
                              void* d_out, int out_size, void* d_ws, size_t ws_size,
                              hipStream_t stream) {
    const int*   w        = (const int*)  d_in[0];
    const int    S        = in_sizes[0];
    const float* emb      = (const float*)d_in[1];
    const float* l1_in_w  = (const float*)d_in[2];
    const float* l1_in_b  = (const float*)d_in[3];
    const float* l1_out_w = (const float*)d_in[4];
    const float* l1_out_b = (const float*)d_in[5];
    const float* l1_w1    = (const float*)d_in[6];
    const float* l1_b1    = (const float*)d_in[7];
    const float* l1_w2    = (const float*)d_in[8];
    const float* l1_b2    = (const float*)d_in[9];
    const float* l2_in_w  = (const float*)d_in[10];
    const float* l2_in_b  = (const float*)d_in[11];
    const float* l2_out_w = (const float*)d_in[12];
    const float* l2_out_b = (const float*)d_in[13];
    const float* l2_w1    = (const float*)d_in[14];
    const float* l2_b1    = (const float*)d_in[15];
    const float* l2_w2    = (const float*)d_in[16];
    const float* l2_b2    = (const float*)d_in[17];
    const float* ow       = (const float*)d_in[18];
    const float* ob       = (const float*)d_in[19];
    float* out = (float*)d_out;

    model_kernel<<<1, 256, 0, stream>>>(w, S, emb,
        l1_in_w, l1_in_b, l1_out_w, l1_out_b, l1_w1, l1_b1, l1_w2, l1_b2,
        l2_in_w, l2_in_b, l2_out_w, l2_out_b, l2_w1, l2_b1, l2_w2, l2_b2,
        ow, ob, out);
}

// Round 2
// 12.638 us; speedup vs baseline: 3.2423x; 3.2423x over previous
//
#include <hip/hip_runtime.h>

// Reduced model: both attention blocks have zero K-projection -> softmax is
// exactly uniform -> attn@v == v(column-mean of src) by linearity. Every
// row of each layer's output depends only on its token id (3 values) and
// the global token histogram. Output = LN(layer2(row_of(w[0]))) . ow + ob.
//
// This version removes the serial-latency tail of R0 (58 us: one thread,
// ~4400 dependent global-load iterations) by (a) staging all weights into
// LDS k-major, (b) computing the 16-dim algebra with 16 lanes + shuffles,
// (c) int4-vectorized histogram.

#define NT 256

// ---- LDS layout (floats) ----
// per layer (stride 1088): vwT@0(256) vb@256(16) owT@272(256) ob@528(16)
//                          w1T@544(256) b1@800(16) w2T@816(256) b2@1072(16)
#define L1   0
#define L2   1088
#define EMB  2176   // 24 floats
#define OWV  2200   // 16 floats

__device__ __forceinline__ float gsum16(float v) {
    v += __shfl_xor(v, 1, 16);
    v += __shfl_xor(v, 2, 16);
    v += __shfl_xor(v, 4, 16);
    v += __shfl_xor(v, 8, 16);
    return v;
}

// layernorm element: (x - mean) / sqrt(E[x^2] - mean^2), group of 16 lanes
__device__ __forceinline__ float lnp(float x) {
    float s  = gsum16(x);
    float s2 = gsum16(x * x);
    float mean = s * 0.0625f;
    float msq  = s2 * 0.0625f;
    return (x - mean) / sqrtf(msq - mean * mean);
}

// y_j = b[j] + sum_k x_k * W[j][k], W stored k-major in LDS (WT[k*16+j])
__device__ __forceinline__ float matT(const float* __restrict__ WT,
                                      const float* __restrict__ b,
                                      float x, int j) {
    float acc = b[j];
    #pragma unroll
    for (int k = 0; k < 16; ++k)
        acc += __shfl(x, k, 16) * WT[k * 16 + j];
    return acc;
}

// one transformer layer, lane-parallel (lane j holds element j)
__device__ __forceinline__ float layer_lane(float src, float meansrc,
                                            const float* __restrict__ L, int j) {
    float vmean = matT(L + 0,   L + 256,  meansrc, j);  // v of mean row
    float a     = matT(L + 272, L + 528,  vmean,   j);  // out proj
    float h     = lnp(src + a);
    float r     = matT(L + 544, L + 800,  h,       j);  // ff1
    r = fmaxf(r, 0.f);
    float y     = h + matT(L + 816, L + 1072, r,   j);  // ff2 + residual
    return lnp(y);
}

__global__ void __launch_bounds__(NT)
model_kernel(const int* __restrict__ w, int S,
             const float* __restrict__ emb,
             const float* __restrict__ l1_in_w, const float* __restrict__ l1_in_b,
             const float* __restrict__ l1_out_w, const float* __restrict__ l1_out_b,
             const float* __restrict__ l1_w1, const float* __restrict__ l1_b1,
             const float* __restrict__ l1_w2, const float* __restrict__ l1_b2,
             const float* __restrict__ l2_in_w, const float* __restrict__ l2_in_b,
             const float* __restrict__ l2_out_w, const float* __restrict__ l2_out_b,
             const float* __restrict__ l2_w1, const float* __restrict__ l2_b1,
             const float* __restrict__ l2_w2, const float* __restrict__ l2_b2,
             const float* __restrict__ ow, const float* __restrict__ ob,
             float* __restrict__ out)
{
    __shared__ float lds[2240];
    __shared__ int cnt[3];
    const int tid = threadIdx.x;
    if (tid < 3) cnt[tid] = 0;

    // ---- stage weights into LDS, 16x16 matrices transposed to k-major ----
    {
        const int jj = tid >> 4, kk = tid & 15;
        const int d = kk * 16 + jj;              // transposed destination
        lds[L1 + 0   + d] = l1_in_w[(32 + jj) * 16 + kk];   // v-block rows 32..47
        lds[L1 + 272 + d] = l1_out_w[tid];
        lds[L1 + 544 + d] = l1_w1[tid];
        lds[L1 + 816 + d] = l1_w2[tid];
        lds[L2 + 0   + d] = l2_in_w[(32 + jj) * 16 + kk];
        lds[L2 + 272 + d] = l2_out_w[tid];
        lds[L2 + 544 + d] = l2_w1[tid];
        lds[L2 + 816 + d] = l2_w2[tid];
    }
    if (tid < 16) {
        lds[L1 + 256  + tid] = l1_in_b[32 + tid];
        lds[L1 + 528  + tid] = l1_out_b[tid];
        lds[L1 + 800  + tid] = l1_b1[tid];
        lds[L1 + 1072 + tid] = l1_b2[tid];
        lds[L2 + 256  + tid] = l2_in_b[32 + tid];
        lds[L2 + 528  + tid] = l2_out_b[tid];
        lds[L2 + 800  + tid] = l2_b1[tid];
        lds[L2 + 1072 + tid] = l2_b2[tid];
        lds[OWV + tid] = ow[tid];
    }
    if (tid < 24) lds[EMB + tid] = emb[tid];

    __syncthreads();   // cnt init + staging visible before atomics/compute

    // ---- token histogram, int4-vectorized ----
    int c0 = 0, c1 = 0, c2 = 0;
    {
        const int n4 = S >> 2;
        const int4* w4 = (const int4*)w;
        for (int i = tid; i < n4; i += NT) {
            int4 t = w4[i];
            c0 += (t.x == 0) + (t.y == 0) + (t.z == 0) + (t.w == 0);
            c1 += (t.x == 1) + (t.y == 1) + (t.z == 1) + (t.w == 1);
            c2 += (t.x == 2) + (t.y == 2) + (t.z == 2) + (t.w == 2);
        }
        for (int i = (n4 << 2) + tid; i < S; i += NT) {
            int t = w[i];
            c0 += (t == 0); c1 += (t == 1); c2 += (t == 2);
        }
    }
    #pragma unroll
    for (int off = 32; off; off >>= 1) {
        c0 += __shfl_down(c0, off);
        c1 += __shfl_down(c1, off);
        c2 += __shfl_down(c2, off);
    }
    if ((tid & 63) == 0) {
        atomicAdd(&cnt[0], c0);
        atomicAdd(&cnt[1], c1);
        atomicAdd(&cnt[2], c2);
    }
    __syncthreads();

    if (tid >= 64) return;   // wave 0 finishes: 16-lane groups, 4x redundant

    const int j  = tid & 15;
    const int jb = j & 7;
    const float sgn  = (j < 8) ? 1.f : -1.f;
    const float invS = 1.f / (float)S;
    const float p0 = cnt[0] * invS, p1 = cnt[1] * invS, p2 = cnt[2] * invS;
    const float* E = lds + EMB;

    // mean input row of layer 1: sum_t p_t * [emb[t], -emb[t]]
    const float meansrc = sgn * (p0 * E[jb] + p1 * E[8 + jb] + p2 * E[16 + jb]);

    // layer-1 output row for each token type (lane j holds element j)
    const float r0 = layer_lane(sgn * E[jb],      meansrc, lds + L1, j);
    const float r1 = layer_lane(sgn * E[8 + jb],  meansrc, lds + L1, j);
    const float r2 = layer_lane(sgn * E[16 + jb], meansrc, lds + L1, j);

    // layer-2
    const float meansrc1 = p0 * r0 + p1 * r1 + p2 * r2;
    const int t0 = w[0];
    const float src2 = (t0 == 0) ? r0 : (t0 == 1 ? r1 : r2);
    const float fin = layer_lane(src2, meansrc1, lds + L2, j);

    const float dot = gsum16(fin * lds[OWV + j]);
    if (tid == 0) out[0] = dot + ob[0];
}

extern "C" void kernel_launch(void* const* d_in, const int* in_sizes, int n_in,
                              void* d_out, int out_size, void* d_ws, size_t ws_size,
                              hipStream_t stream) {
    const int*   w        = (const int*)  d_in[0];
    const int    S        = in_sizes[0];
    const float* emb      = (const float*)d_in[1];
    const float* l1_in_w  = (const float*)d_in[2];
    const float* l1_in_b  = (const float*)d_in[3];
    const float* l1_out_w = (const float*)d_in[4];
    const float* l1_out_b = (const float*)d_in[5];
    const float* l1_w1    = (const float*)d_in[6];
    const float* l1_b1    = (const float*)d_in[7];
    const float* l1_w2    = (const float*)d_in[8];
    const float* l1_b2    = (const float*)d_in[9];
    const float* l2_in_w  = (const float*)d_in[10];
    const float* l2_in_b  = (const float*)d_in[11];
    const float* l2_out_w = (const float*)d_in[12];
    const float* l2_out_b = (const float*)d_in[13];
    const float* l2_w1    = (const float*)d_in[14];
    const float* l2_b1    = (const float*)d_in[15];
    const float* l2_w2    = (const float*)d_in[16];
    const float* l2_b2    = (const float*)d_in[17];
    const float* ow       = (const float*)d_in[18];
    const float* ob       = (const float*)d_in[19];
    float* out = (float*)d_out;

    model_kernel<<<1, NT, 0, stream>>>(w, S, emb,
        l1_in_w, l1_in_b, l1_out_w, l1_out_b, l1_w1, l1_b1, l1_w2, l1_b2,
        l2_in_w, l2_in_b, l2_out_w, l2_out_b, l2_w1, l2_b1, l2_w2, l2_b2,
        ow, ob, out);
}

// Round 3
// 9.930 us; speedup vs baseline: 4.1265x; 1.2727x over previous
//
#include <hip/hip_runtime.h>

// Reduced model: both attention K-projections are zero -> softmax exactly
// uniform -> attn@v == v(mean row). Each output row depends only on its
// token id (3 types) and the token histogram. out = LN2(row(w[0])).ow + ob.
//
// R2 version: all-register weights (no LDS staging), rsqrtf layernorm,
// prefetched w[0], fully-unrolled histogram loads. LDS = 3 counters only.

#define NT 256

struct LayerRegs {
    float4 vw[4], ow[4], w1[4], w2[4];   // lane j holds row j of each matrix
    float vb, ob_, b1, b2;
};

__device__ __forceinline__ float gsum16(float v) {
    v += __shfl_xor(v, 1, 16);
    v += __shfl_xor(v, 2, 16);
    v += __shfl_xor(v, 4, 16);
    v += __shfl_xor(v, 8, 16);
    return v;
}

// layernorm element over a 16-lane group: (x - mean) * rsqrt(E[x^2]-mean^2)
__device__ __forceinline__ float lnp(float x) {
    float s  = gsum16(x);
    float s2 = gsum16(x * x);
    float mean = s * 0.0625f;
    float msq  = s2 * 0.0625f;
    return (x - mean) * rsqrtf(msq - mean * mean);
}

// y_j = b + sum_k x_k * W[j][k]; row j in 4 float4 regs, static indexing only
__device__ __forceinline__ float matR(const float4* __restrict__ W, float b, float x) {
    float a0 = b, a1 = 0.f;
    #pragma unroll
    for (int kq = 0; kq < 4; ++kq) {
        float4 wv = W[kq];
        a0 += __shfl(x, 4 * kq + 0, 16) * wv.x;
        a1 += __shfl(x, 4 * kq + 1, 16) * wv.y;
        a0 += __shfl(x, 4 * kq + 2, 16) * wv.z;
        a1 += __shfl(x, 4 * kq + 3, 16) * wv.w;
    }
    return a0 + a1;
}

// one transformer layer, lane-parallel (lane j holds element j)
__device__ __forceinline__ float layer_lane(float src, float meansrc,
                                            const LayerRegs& L) {
    float vmean = matR(L.vw, L.vb,  meansrc);   // v of mean row
    float a     = matR(L.ow, L.ob_, vmean);     // out projection
    float h     = lnp(src + a);
    float r     = fmaxf(matR(L.w1, L.b1, h), 0.f);
    float y     = h + matR(L.w2, L.b2, r);
    return lnp(y);
}

#define LOADROW(dst, ptr, row) {                         \
    const float4* _p = (const float4*)(ptr) + (row) * 4; \
    dst[0] = _p[0]; dst[1] = _p[1];                      \
    dst[2] = _p[2]; dst[3] = _p[3]; }

__global__ void __launch_bounds__(NT)
model_kernel(const int* __restrict__ w, int S,
             const float* __restrict__ emb,
             const float* __restrict__ l1_in_w, const float* __restrict__ l1_in_b,
             const float* __restrict__ l1_out_w, const float* __restrict__ l1_out_b,
             const float* __restrict__ l1_w1, const float* __restrict__ l1_b1,
             const float* __restrict__ l1_w2, const float* __restrict__ l1_b2,
             const float* __restrict__ l2_in_w, const float* __restrict__ l2_in_b,
             const float* __restrict__ l2_out_w, const float* __restrict__ l2_out_b,
             const float* __restrict__ l2_w1, const float* __restrict__ l2_b1,
             const float* __restrict__ l2_w2, const float* __restrict__ l2_b2,
             const float* __restrict__ ow, const float* __restrict__ ob,
             float* __restrict__ out)
{
    __shared__ int cnt[2];
    const int tid = threadIdx.x;
    const int j   = tid & 15;
    const int jb  = j & 7;
    const bool w0wave = (tid < 64);
    if (tid < 2) cnt[tid] = 0;

    // ---- wave 0: issue ALL compute-side loads up front (regs, coalesced) ----
    LayerRegs R1, R2;
    float e0 = 0.f, e1 = 0.f, e2 = 0.f, owj = 0.f, ob0 = 0.f;
    int t0 = 0;
    if (w0wave) {
        t0 = w[0];
        LOADROW(R1.vw, l1_in_w, 32 + j);   // v-block rows 32..47
        LOADROW(R1.ow, l1_out_w, j);
        LOADROW(R1.w1, l1_w1, j);
        LOADROW(R1.w2, l1_w2, j);
        LOADROW(R2.vw, l2_in_w, 32 + j);
        LOADROW(R2.ow, l2_out_w, j);
        LOADROW(R2.w1, l2_w1, j);
        LOADROW(R2.w2, l2_w2, j);
        R1.vb = l1_in_b[32 + j]; R1.ob_ = l1_out_b[j];
        R1.b1 = l1_b1[j];        R1.b2  = l1_b2[j];
        R2.vb = l2_in_b[32 + j]; R2.ob_ = l2_out_b[j];
        R2.b1 = l2_b1[j];        R2.b2  = l2_b2[j];
        e0 = emb[jb]; e1 = emb[8 + jb]; e2 = emb[16 + jb];
        owj = ow[j];  ob0 = ob[0];
    }
    const float invS = 1.f / (float)S;   // off critical path (issued early)

    // ---- token histogram (c2 derived as S - c0 - c1) ----
    int c0 = 0, c1 = 0;
    if (S == NT * 32) {                  // fast path: 8 int4 loads, one latency
        const int4* w4 = (const int4*)w;
        int4 t[8];
        #pragma unroll
        for (int u = 0; u < 8; ++u) t[u] = w4[tid + u * NT];
        #pragma unroll
        for (int u = 0; u < 8; ++u) {
            c0 += (t[u].x == 0) + (t[u].y == 0) + (t[u].z == 0) + (t[u].w == 0);
            c1 += (t[u].x == 1) + (t[u].y == 1) + (t[u].z == 1) + (t[u].w == 1);
        }
    } else {
        for (int i = tid; i < S; i += NT) {
            int t = w[i];
            c0 += (t == 0); c1 += (t == 1);
        }
    }
    #pragma unroll
    for (int off = 32; off; off >>= 1) {
        c0 += __shfl_down(c0, off);
        c1 += __shfl_down(c1, off);
    }
    __syncthreads();                     // cnt init visible
    if ((tid & 63) == 0) {
        atomicAdd(&cnt[0], c0);
        atomicAdd(&cnt[1], c1);
    }
    __syncthreads();
    if (!w0wave) return;

    // ---- 16-dim algebra on wave 0 (4 redundant 16-lane groups) ----
    const float p0 = cnt[0] * invS;
    const float p1 = cnt[1] * invS;
    const float p2 = 1.f - p0 - p1;
    const float sgn = (j < 8) ? 1.f : -1.f;

    // mean input row of layer 1: sum_t p_t * [emb[t], -emb[t]]
    const float meansrc = sgn * (p0 * e0 + p1 * e1 + p2 * e2);

    // layer-1 output rows for the 3 token types (independent -> ILP)
    const float r0 = layer_lane(sgn * e0, meansrc, R1);
    const float r1 = layer_lane(sgn * e1, meansrc, R1);
    const float r2 = layer_lane(sgn * e2, meansrc, R1);

    // layer 2 on row of token w[0]
    const float meansrc1 = p0 * r0 + p1 * r1 + p2 * r2;
    const float src2 = (t0 == 0) ? r0 : (t0 == 1 ? r1 : r2);
    const float fin = layer_lane(src2, meansrc1, R2);

    const float dot = gsum16(fin * owj);
    if (tid == 0) out[0] = dot + ob0;
}

extern "C" void kernel_launch(void* const* d_in, const int* in_sizes, int n_in,
                              void* d_out, int out_size, void* d_ws, size_t ws_size,
                              hipStream_t stream) {
    const int*   w        = (const int*)  d_in[0];
    const int    S        = in_sizes[0];
    const float* emb      = (const float*)d_in[1];
    const float* l1_in_w  = (const float*)d_in[2];
    const float* l1_in_b  = (const float*)d_in[3];
    const float* l1_out_w = (const float*)d_in[4];
    const float* l1_out_b = (const float*)d_in[5];
    const float* l1_w1    = (const float*)d_in[6];
    const float* l1_b1    = (const float*)d_in[7];
    const float* l1_w2    = (const float*)d_in[8];
    const float* l1_b2    = (const float*)d_in[9];
    const float* l2_in_w  = (const float*)d_in[10];
    const float* l2_in_b  = (const float*)d_in[11];
    const float* l2_out_w = (const float*)d_in[12];
    const float* l2_out_b = (const float*)d_in[13];
    const float* l2_w1    = (const float*)d_in[14];
    const float* l2_b1    = (const float*)d_in[15];
    const float* l2_w2    = (const float*)d_in[16];
    const float* l2_b2    = (const float*)d_in[17];
    const float* ow       = (const float*)d_in[18];
    const float* ob       = (const float*)d_in[19];
    float* out = (float*)d_out;

    model_kernel<<<1, NT, 0, stream>>>(w, S, emb,
        l1_in_w, l1_in_b, l1_out_w, l1_out_b, l1_w1, l1_b1, l1_w2, l1_b2,
        l2_in_w, l2_in_b, l2_out_w, l2_out_b, l2_w1, l2_b1, l2_w2, l2_b2,
        ow, ob, out);
}

// Round 4
// 9.755 us; speedup vs baseline: 4.2006x; 1.0180x over previous
//
#include <hip/hip_runtime.h>

// Reduced model: both attention K-projections are zero -> softmax exactly
// uniform -> attn@v == v(mean row). Each row of each layer's output depends
// only on its token id (3 types) and the token histogram.
// out = LN(layer2(row(w[0]))) . ow + ob.
//
// R4 version:
//  - wave specialization: waves 1-3 do the histogram while wave 0 precomputes
//    the histogram-independent linear part of attention (a = sum p_t u_t + c)
//  - 16-lane groups of wave 0 each own one token type (no redundant layer-1)
//  - single __syncthreads, no LDS atomics (per-wave partials, packed counts)
//  - all 16-lane broadcasts / xor-reduces are single ds_swizzle_b32 ops

#define NT 256

template<int K> __device__ __forceinline__ float bc16(float v) {
    // broadcast lane K within each 16-lane group: and=0x10, or=K, xor=0
    return __int_as_float(__builtin_amdgcn_ds_swizzle(__float_as_int(v), 0x10 | (K << 5)));
}
template<int M> __device__ __forceinline__ float xr16(float v) {
    // lane ^= M within 32 (M<16 stays inside the 16-group): and=0x1f, xor=M
    return __int_as_float(__builtin_amdgcn_ds_swizzle(__float_as_int(v), 0x1f | (M << 10)));
}

__device__ __forceinline__ float gsum16(float v) {
    v += xr16<1>(v); v += xr16<2>(v); v += xr16<4>(v); v += xr16<8>(v);
    return v;
}

// layernorm element over a 16-lane group: (x - mean) * rsqrt(E[x^2]-mean^2)
__device__ __forceinline__ float lnp(float x) {
    float s  = gsum16(x);
    float s2 = gsum16(x * x);
    float mean = s * 0.0625f;
    float msq  = s2 * 0.0625f;
    return (x - mean) * rsqrtf(msq - mean * mean);
}

struct LayerRegs {
    float4 vw[4], ow[4], w1[4], w2[4];   // lane j holds row j of each matrix
    float vb, ob_, b1, b2;
};

// y_j = b + sum_k x_k * W[j][k]; row j of W in 4 float4 regs (lane-sliced x)
__device__ __forceinline__ float matR(const float4* __restrict__ W, float b, float x) {
    float a0 = b, a1 = 0.f;
    a0 += bc16<0 >(x) * W[0].x;  a1 += bc16<1 >(x) * W[0].y;
    a0 += bc16<2 >(x) * W[0].z;  a1 += bc16<3 >(x) * W[0].w;
    a0 += bc16<4 >(x) * W[1].x;  a1 += bc16<5 >(x) * W[1].y;
    a0 += bc16<6 >(x) * W[1].z;  a1 += bc16<7 >(x) * W[1].w;
    a0 += bc16<8 >(x) * W[2].x;  a1 += bc16<9 >(x) * W[2].y;
    a0 += bc16<10>(x) * W[2].z;  a1 += bc16<11>(x) * W[2].w;
    a0 += bc16<12>(x) * W[3].x;  a1 += bc16<13>(x) * W[3].y;
    a0 += bc16<14>(x) * W[3].z;  a1 += bc16<15>(x) * W[3].w;
    return a0 + a1;
}

#define LOADROW(dst, ptr, row) {                         \
    const float4* _p = (const float4*)(ptr) + (row) * 4; \
    dst[0] = _p[0]; dst[1] = _p[1];                      \
    dst[2] = _p[2]; dst[3] = _p[3]; }

__global__ void __launch_bounds__(NT)
model_kernel(const int* __restrict__ wtok, int S,
             const float* __restrict__ emb,
             const float* __restrict__ l1_in_w, const float* __restrict__ l1_in_b,
             const float* __restrict__ l1_out_w, const float* __restrict__ l1_out_b,
             const float* __restrict__ l1_w1, const float* __restrict__ l1_b1,
             const float* __restrict__ l1_w2, const float* __restrict__ l1_b2,
             const float* __restrict__ l2_in_w, const float* __restrict__ l2_in_b,
             const float* __restrict__ l2_out_w, const float* __restrict__ l2_out_b,
             const float* __restrict__ l2_w1, const float* __restrict__ l2_b1,
             const float* __restrict__ l2_w2, const float* __restrict__ l2_b2,
             const float* __restrict__ ow, const float* __restrict__ ob,
             float* __restrict__ out)
{
    __shared__ int part[3];              // per-wave packed histogram partials
    const int tid = threadIdx.x;
    const int j   = tid & 15;            // element slot within 16-group
    const int jb  = j & 7;
    const int grp = (tid >> 4) & 3;      // 16-lane group id within wave 0
    const bool w0 = (tid < 64);
    const float sgn = (j < 8) ? 1.f : -1.f;

    // ---- wave 0: issue all compute-side loads up front ----
    LayerRegs R1, R2;
    float eg = 0.f, owj = 0.f, ob0 = 0.f;
    int t0 = 0;
    if (w0) {
        t0 = wtok[0];
        LOADROW(R1.vw, l1_in_w, 32 + j);     // v-block rows 32..47
        LOADROW(R1.ow, l1_out_w, j);
        LOADROW(R1.w1, l1_w1, j);
        LOADROW(R1.w2, l1_w2, j);
        LOADROW(R2.vw, l2_in_w, 32 + j);
        LOADROW(R2.ow, l2_out_w, j);
        LOADROW(R2.w1, l2_w1, j);
        LOADROW(R2.w2, l2_w2, j);
        R1.vb = l1_in_b[32 + j]; R1.ob_ = l1_out_b[j];
        R1.b1 = l1_b1[j];        R1.b2  = l1_b2[j];
        R2.vb = l2_in_b[32 + j]; R2.ob_ = l2_out_b[j];
        R2.b1 = l2_b1[j];        R2.b2  = l2_b2[j];
        eg  = emb[((grp < 2) ? grp : 2) * 8 + jb];   // group's token embedding
        owj = ow[j]; ob0 = ob[0];
    }
    const float invS = 1.f / (float)S;

    float u = 0.f, cvec = 0.f;
    if (!w0) {
        // ---- waves 1-3: token histogram (c1, c2 packed; c0 derived) ----
        int c1 = 0, c2 = 0;
        const int idx = tid - 64;            // 0..191
        const int n4 = S >> 2;
        const int4* w4 = (const int4*)wtok;
        for (int i = idx; i < n4; i += 192) {
            int4 t = w4[i];
            c1 += (t.x == 1) + (t.y == 1) + (t.z == 1) + (t.w == 1);
            c2 += (t.x == 2) + (t.y == 2) + (t.z == 2) + (t.w == 2);
        }
        for (int i = (n4 << 2) + idx; i < S; i += 192) {
            int t = wtok[i];
            c1 += (t == 1); c2 += (t == 2);
        }
        int pack = c1 | (c2 << 16);
        #pragma unroll
        for (int off = 32; off; off >>= 1) pack += __shfl_down(pack, off);
        if ((tid & 63) == 0) part[(tid >> 6) - 1] = pack;
    } else {
        // ---- wave 0: histogram-independent attention precompute ----
        // a = sum_t p_t * (ow@vw@m_t) + (ow@vb + ob); group g computes u_g
        u    = matR(R1.ow, 0.f, matR(R1.vw, 0.f, sgn * eg));
        cvec = matR(R1.ow, R1.ob_, R1.vb);
    }
    __syncthreads();
    if (!w0) return;

    // ---- probabilities ----
    const int pk = part[0] + part[1] + part[2];
    const float p1 = (float)(pk & 0xffff) * invS;
    const float p2 = (float)(pk >> 16)    * invS;
    const float p0 = 1.f - p1 - p2;

    // attention output row (same for every row): gather u across groups
    const float a = cvec + p0 * __shfl(u, j, 64)
                         + p1 * __shfl(u, j + 16, 64)
                         + p2 * __shfl(u, j + 32, 64);

    // ---- layer 1 for this group's token ----
    const float h  = lnp(sgn * eg + a);
    const float rr = fmaxf(matR(R1.w1, R1.b1, h), 0.f);
    const float y  = h + matR(R1.w2, R1.b2, rr);
    const float r  = lnp(y);

    // ---- layer 2 (redundant across groups) ----
    const float ms1 = p0 * __shfl(r, j, 64)
                    + p1 * __shfl(r, j + 16, 64)
                    + p2 * __shfl(r, j + 32, 64);
    const float src2 = __shfl(r, j + (t0 << 4), 64);

    const float vm2 = matR(R2.vw, R2.vb, ms1);
    const float a2  = matR(R2.ow, R2.ob_, vm2);
    const float h2  = lnp(src2 + a2);
    const float rr2 = fmaxf(matR(R2.w1, R2.b1, h2), 0.f);
    const float y2  = h2 + matR(R2.w2, R2.b2, rr2);
    const float fin = lnp(y2);

    const float dot = gsum16(fin * owj);
    if (tid == 0) out[0] = dot + ob0;
}

extern "C" void kernel_launch(void* const* d_in, const int* in_sizes, int n_in,
                              void* d_out, int out_size, void* d_ws, size_t ws_size,
                              hipStream_t stream) {
    const int*   w        = (const int*)  d_in[0];
    const int    S        = in_sizes[0];
    const float* emb      = (const float*)d_in[1];
    const float* l1_in_w  = (const float*)d_in[2];
    const float* l1_in_b  = (const float*)d_in[3];
    const float* l1_out_w = (const float*)d_in[4];
    const float* l1_out_b = (const float*)d_in[5];
    const float* l1_w1    = (const float*)d_in[6];
    const float* l1_b1    = (const float*)d_in[7];
    const float* l1_w2    = (const float*)d_in[8];
    const float* l1_b2    = (const float*)d_in[9];
    const float* l2_in_w  = (const float*)d_in[10];
    const float* l2_in_b  = (const float*)d_in[11];
    const float* l2_out_w = (const float*)d_in[12];
    const float* l2_out_b = (const float*)d_in[13];
    const float* l2_w1    = (const float*)d_in[14];
    const float* l2_b1    = (const float*)d_in[15];
    const float* l2_w2    = (const float*)d_in[16];
    const float* l2_b2    = (const float*)d_in[17];
    const float* ow       = (const float*)d_in[18];
    const float* ob       = (const float*)d_in[19];
    float* out = (float*)d_out;

    model_kernel<<<1, NT, 0, stream>>>(w, S, emb,
        l1_in_w, l1_in_b, l1_out_w, l1_out_b, l1_w1, l1_b1, l1_w2, l1_b2,
        l2_in_w, l2_in_b, l2_out_w, l2_out_b, l2_w1, l2_b1, l2_w2, l2_b2,
        ow, ob, out);
}